// Round 1
// baseline (443.532 us; speedup 1.0000x reference)
//
#include <hip/hip_runtime.h>

#define H128   128
#define K256   256
#define TILE_E 128

typedef __attribute__((ext_vector_type(8))) short bf16x8;
typedef __attribute__((ext_vector_type(4))) float floatx4;

__device__ __forceinline__ unsigned short f2bf(float f) {
  union { float f; unsigned u; } v; v.f = f;
  return (unsigned short)((v.u + 0x7FFFu + ((v.u >> 16) & 1u)) >> 16);  // RNE
}

__device__ __forceinline__ bf16x8 pack8(float4 a, float4 b) {
  bf16x8 r;
  r[0] = (short)f2bf(a.x); r[1] = (short)f2bf(a.y);
  r[2] = (short)f2bf(a.z); r[3] = (short)f2bf(a.w);
  r[4] = (short)f2bf(b.x); r[5] = (short)f2bf(b.y);
  r[6] = (short)f2bf(b.z); r[7] = (short)f2bf(b.w);
  return r;
}

__global__ void cvt_kernel(const float* __restrict__ in,
                           unsigned short* __restrict__ out, int n4) {
  int i = blockIdx.x * blockDim.x + threadIdx.x;
  int stride = gridDim.x * blockDim.x;
  for (; i < n4; i += stride) {
    float4 v = ((const float4*)in)[i];
    ushort4 o;
    o.x = f2bf(v.x); o.y = f2bf(v.y); o.z = f2bf(v.z); o.w = f2bf(v.w);
    ((ushort4*)out)[i] = o;
  }
}

// Wave w: eh = w&1 -> edges [eh*64, eh*64+64); nh = w>>1 -> outs [nh*64, nh*64+64).
// W1 B-fragments register-resident (32 frags); A-frags from XOR-swizzled LDS tile.
template <bool PRE>
__global__ __launch_bounds__(256, 2)
void edge_decoder(const float* __restrict__ zsrc_f, const float* __restrict__ zdst_f,
                  const unsigned short* __restrict__ zsrc_b,
                  const unsigned short* __restrict__ zdst_b,
                  const int* __restrict__ eidx,
                  const float* __restrict__ W1f, const unsigned short* __restrict__ W1b,
                  const float* __restrict__ b1, const float* __restrict__ W2,
                  const float* __restrict__ b2,
                  float* __restrict__ out, int E)
{
  __shared__ unsigned short Zt[TILE_E * K256];   // 64 KiB: rows of 256 bf16, 16B-chunk XOR swizzle

  const int tid  = threadIdx.x;
  const int wave = tid >> 6;
  const int lane = tid & 63;
  const int nlo  = lane & 15;
  const int quad = lane >> 4;
  const int eh   = wave & 1;
  const int nh   = wave >> 1;
  const int e0   = blockIdx.x * TILE_E;
  const int nE   = min(TILE_E, E - e0);

  // ---- preload W1 B-fragments: B[k][n] = W1[n][k], 8 consecutive k per lane ----
  bf16x8 w1f[4][8];
  const int nb = nh * 64;
#pragma unroll
  for (int nt = 0; nt < 4; ++nt) {
    const int n = nb + nt * 16 + nlo;
#pragma unroll
    for (int kt = 0; kt < 8; ++kt) {
      const int k = kt * 32 + quad * 8;
      if (PRE) {
        w1f[nt][kt] = *(const bf16x8*)(W1b + n * K256 + k);
      } else {
        const float* p = W1f + n * K256 + k;
        w1f[nt][kt] = pack8(*(const float4*)p, *(const float4*)(p + 4));
      }
    }
  }

  // ---- gather: 16 lanes per (edge, half), 16B per lane, swizzled LDS write ----
  {
    const int g   = tid >> 4;   // 0..15
    const int l16 = tid & 15;
#pragma unroll
    for (int it = 0; it < 16; ++it) {
      const int hidx = g + it * 16;
      if (hidx < nE * 2) {
        const int e = hidx >> 1, h = hidx & 1;
        const int node = eidx[h * E + e0 + e];
        const int cs = (((h << 4) | l16) ^ (e & 31));
        bf16x8 v;
        if (PRE) {
          const unsigned short* s = (h ? zdst_b : zsrc_b) + node * H128 + l16 * 8;
          v = *(const bf16x8*)s;
        } else {
          const float* s = (h ? zdst_f : zsrc_f) + node * H128 + l16 * 8;
          v = pack8(*(const float4*)s, *(const float4*)(s + 4));
        }
        *(bf16x8*)(Zt + e * K256 + cs * 8) = v;
      }
    }
  }
  __syncthreads();

  // ---- K-loop: 4 A-reads feed 16 MFMAs per kt ----
  floatx4 acc[4][4];
#pragma unroll
  for (int mt = 0; mt < 4; ++mt)
#pragma unroll
    for (int nt = 0; nt < 4; ++nt)
      acc[mt][nt] = (floatx4){0.f, 0.f, 0.f, 0.f};

#pragma unroll
  for (int kt = 0; kt < 8; ++kt) {
    bf16x8 a[4];
#pragma unroll
    for (int mt = 0; mt < 4; ++mt) {
      const int m  = eh * 64 + mt * 16 + nlo;
      const int cs = (kt * 4 + quad) ^ (m & 31);
      a[mt] = *(const bf16x8*)(Zt + m * K256 + cs * 8);
    }
#pragma unroll
    for (int mt = 0; mt < 4; ++mt)
#pragma unroll
      for (int nt = 0; nt < 4; ++nt)
        acc[mt][nt] = __builtin_amdgcn_mfma_f32_16x16x32_bf16(
            a[mt], w1f[nt][kt], acc[mt][nt], 0, 0, 0);
  }

  // ---- epilogue: +b1, relu, dot W2 over this wave's 64 outs ----
  float b1v[4], w2v[4];
#pragma unroll
  for (int nt = 0; nt < 4; ++nt) {
    const int n = nb + nt * 16 + nlo;
    b1v[nt] = b1[n];
    w2v[nt] = W2[n];
  }
  float vv[4][4];
#pragma unroll
  for (int mt = 0; mt < 4; ++mt) {
#pragma unroll
    for (int r = 0; r < 4; ++r) {
      float v = 0.f;
#pragma unroll
      for (int nt = 0; nt < 4; ++nt) {
        float x = acc[mt][nt][r] + b1v[nt];
        x = fmaxf(x, 0.f);
        v = fmaf(x, w2v[nt], v);
      }
      v += __shfl_xor(v, 1);
      v += __shfl_xor(v, 2);
      v += __shfl_xor(v, 4);
      v += __shfl_xor(v, 8);
      vv[mt][r] = v;
    }
  }

  __syncthreads();               // all Zt reads complete -> safe to overlay
  float* part = (float*)Zt;      // part[nh*128 + e_local], 1 KiB
  if (nlo == 0) {
#pragma unroll
    for (int mt = 0; mt < 4; ++mt)
#pragma unroll
      for (int r = 0; r < 4; ++r)
        part[nh * TILE_E + eh * 64 + mt * 16 + quad * 4 + r] = vv[mt][r];
  }
  __syncthreads();
  if (tid < nE)
    out[e0 + tid] = part[tid] + part[TILE_E + tid] + b2[0];
}

extern "C" void kernel_launch(void* const* d_in, const int* in_sizes, int n_in,
                              void* d_out, int out_size, void* d_ws, size_t ws_size,
                              hipStream_t stream) {
  const float* z_src = (const float*)d_in[0];
  const float* z_dst = (const float*)d_in[1];
  const int*   eidx  = (const int*)d_in[2];
  const float* W1    = (const float*)d_in[3];
  const float* b1    = (const float*)d_in[4];
  const float* W2    = (const float*)d_in[5];
  const float* b2    = (const float*)d_in[6];
  float* out = (float*)d_out;

  const int NH   = in_sizes[0];       // 12,800,000
  const int E    = in_sizes[2] / 2;   // 1,000,000
  const int W1n  = in_sizes[3];       // 32,768
  const int nblk = (E + TILE_E - 1) / TILE_E;

  const size_t need = ((size_t)NH * 2 + (size_t)W1n) * sizeof(unsigned short);
  if (ws_size >= need) {
    unsigned short* zsb = (unsigned short*)d_ws;
    unsigned short* zdb = zsb + NH;
    unsigned short* w1b = zdb + NH;
    cvt_kernel<<<2048, 256, 0, stream>>>(z_src, zsb, NH / 4);
    cvt_kernel<<<2048, 256, 0, stream>>>(z_dst, zdb, NH / 4);
    cvt_kernel<<<32, 256, 0, stream>>>(W1, w1b, W1n / 4);
    edge_decoder<true><<<nblk, 256, 0, stream>>>(
        nullptr, nullptr, zsb, zdb, eidx, nullptr, w1b, b1, W2, b2, out, E);
  } else {
    edge_decoder<false><<<nblk, 256, 0, stream>>>(
        z_src, z_dst, nullptr, nullptr, eidx, W1, nullptr, b1, W2, b2, out, E);
  }
}

// Round 2
// 285.290 us; speedup vs baseline: 1.5547x; 1.5547x over previous
//
#include <hip/hip_runtime.h>

#define H128   128
#define K256   256
#define TILE_E 64

typedef __attribute__((ext_vector_type(8))) short bf16x8;
typedef __attribute__((ext_vector_type(4))) float floatx4;

__device__ __forceinline__ unsigned short f2bf(float f) {
  union { float f; unsigned u; } v; v.f = f;
  return (unsigned short)((v.u + 0x7FFFu + ((v.u >> 16) & 1u)) >> 16);  // RNE
}

__device__ __forceinline__ bf16x8 pack8(float4 a, float4 b) {
  bf16x8 r;
  r[0] = (short)f2bf(a.x); r[1] = (short)f2bf(a.y);
  r[2] = (short)f2bf(a.z); r[3] = (short)f2bf(a.w);
  r[4] = (short)f2bf(b.x); r[5] = (short)f2bf(b.y);
  r[6] = (short)f2bf(b.z); r[7] = (short)f2bf(b.w);
  return r;
}

// One launch converts z_src, z_dst, W1 (fp32 -> bf16), float4-granular.
__global__ __launch_bounds__(256, 8)
void cvt3_kernel(const float* __restrict__ a, unsigned short* __restrict__ oa, int na4,
                 const float* __restrict__ b, unsigned short* __restrict__ ob, int nb4,
                 const float* __restrict__ c, unsigned short* __restrict__ oc, int nc4) {
  int i = blockIdx.x * blockDim.x + threadIdx.x;
  const int stride = gridDim.x * blockDim.x;
  const int total = na4 + nb4 + nc4;
  for (; i < total; i += stride) {
    const float* src; unsigned short* dst; int j = i;
    if (j < na4)               { src = a; dst = oa; }
    else if ((j -= na4) < nb4) { src = b; dst = ob; }
    else                       { j -= nb4; src = c; dst = oc; }
    float4 v = ((const float4*)src)[j];
    ushort4 o;
    o.x = f2bf(v.x); o.y = f2bf(v.y); o.z = f2bf(v.z); o.w = f2bf(v.w);
    ((ushort4*)dst)[j] = o;
  }
}

// 64-edge tile, 32 KB LDS -> 4 blocks/CU. Wave w owns out-quarter nh=w (32 outs),
// all 64 edges. Edge indices pre-staged to LDS (one coalesced load) so the gather
// loop has no global->global dependent chain and no branches.
template <bool PRE>
__global__ __launch_bounds__(256, 4)
void edge_decoder(const float* __restrict__ zsrc_f, const float* __restrict__ zdst_f,
                  const unsigned short* __restrict__ zsrc_b,
                  const unsigned short* __restrict__ zdst_b,
                  const int* __restrict__ eidx,
                  const float* __restrict__ W1f, const unsigned short* __restrict__ W1b,
                  const float* __restrict__ b1, const float* __restrict__ W2,
                  const float* __restrict__ b2,
                  float* __restrict__ out, int E)
{
  __shared__ unsigned short Zt[TILE_E * K256];  // 32 KiB, 16B-chunk XOR swizzle
  __shared__ int   idxs[2 * TILE_E];            // 512 B
  __shared__ float part[4 * TILE_E];            // 1 KiB

  const int tid  = threadIdx.x;
  const int lane = tid & 63;
  const int nh   = tid >> 6;          // wave id -> out-quarter
  const int nlo  = lane & 15;
  const int quad = lane >> 4;
  const int e0   = blockIdx.x * TILE_E;

  // ---- stage edge indices: idxs[h*64 + e] ----
  if (tid < 2 * TILE_E) {
    const int ee = e0 + (tid & 63);
    idxs[tid] = (ee < E) ? eidx[(tid >> 6) * E + ee] : 0;
  }
  __syncthreads();

  // ---- gather: 8 independent 16B loads per thread, branch-free ----
#pragma unroll
  for (int it = 0; it < 8; ++it) {
    const int c   = tid + it * 256;   // chunk id 0..2047
    const int row = c >> 4;           // 0..127 = e*2+h
    const int l16 = c & 15;
    const int e   = row >> 1;
    const int h   = row & 1;
    const int node = idxs[h * TILE_E + e];   // LDS broadcast within 16-lane group
    const int cs  = ((h << 4) | l16) ^ (e & 31);
    bf16x8 v;
    if (PRE) {
      const unsigned short* s = (h ? zdst_b : zsrc_b) + node * H128 + l16 * 8;
      v = *(const bf16x8*)s;
    } else {
      const float* p = (h ? zdst_f : zsrc_f) + node * H128 + l16 * 8;
      v = pack8(*(const float4*)p, *(const float4*)(p + 4));
    }
    *(bf16x8*)(Zt + e * K256 + cs * 8) = v;
  }
  __syncthreads();

  // ---- W1 B-fragments for this wave's 32 outs ----
  bf16x8 w1f[2][8];
  const int nb = nh * 32;
#pragma unroll
  for (int nt = 0; nt < 2; ++nt) {
    const int n = nb + nt * 16 + nlo;
#pragma unroll
    for (int kt = 0; kt < 8; ++kt) {
      const int k = kt * 32 + quad * 8;
      if (PRE) {
        w1f[nt][kt] = *(const bf16x8*)(W1b + n * K256 + k);
      } else {
        const float* p = W1f + n * K256 + k;
        w1f[nt][kt] = pack8(*(const float4*)p, *(const float4*)(p + 4));
      }
    }
  }

  // ---- K-loop: 4 A-reads feed 8 MFMAs per kt ----
  floatx4 acc[4][2];
#pragma unroll
  for (int mt = 0; mt < 4; ++mt)
#pragma unroll
    for (int nt = 0; nt < 2; ++nt)
      acc[mt][nt] = (floatx4){0.f, 0.f, 0.f, 0.f};

#pragma unroll
  for (int kt = 0; kt < 8; ++kt) {
    bf16x8 a[4];
#pragma unroll
    for (int mt = 0; mt < 4; ++mt) {
      const int m  = mt * 16 + nlo;
      const int cs = (kt * 4 + quad) ^ (m & 31);
      a[mt] = *(const bf16x8*)(Zt + m * K256 + cs * 8);
    }
#pragma unroll
    for (int mt = 0; mt < 4; ++mt)
#pragma unroll
      for (int nt = 0; nt < 2; ++nt)
        acc[mt][nt] = __builtin_amdgcn_mfma_f32_16x16x32_bf16(
            a[mt], w1f[nt][kt], acc[mt][nt], 0, 0, 0);
  }

  // ---- epilogue: +b1, relu, dot W2 over this wave's 32 outs, 16-lane reduce ----
  float b1v[2], w2v[2];
#pragma unroll
  for (int nt = 0; nt < 2; ++nt) {
    const int n = nb + nt * 16 + nlo;
    b1v[nt] = b1[n];
    w2v[nt] = W2[n];
  }
#pragma unroll
  for (int mt = 0; mt < 4; ++mt) {
#pragma unroll
    for (int r = 0; r < 4; ++r) {
      float v = 0.f;
#pragma unroll
      for (int nt = 0; nt < 2; ++nt) {
        float x = acc[mt][nt][r] + b1v[nt];
        x = fmaxf(x, 0.f);
        v = fmaf(x, w2v[nt], v);
      }
      v += __shfl_xor(v, 1);
      v += __shfl_xor(v, 2);
      v += __shfl_xor(v, 4);
      v += __shfl_xor(v, 8);
      if (nlo == 0)
        part[nh * TILE_E + mt * 16 + quad * 4 + r] = v;
    }
  }
  __syncthreads();
  if (tid < TILE_E && e0 + tid < E)
    out[e0 + tid] = part[tid] + part[TILE_E + tid] + part[2 * TILE_E + tid]
                  + part[3 * TILE_E + tid] + b2[0];
}

extern "C" void kernel_launch(void* const* d_in, const int* in_sizes, int n_in,
                              void* d_out, int out_size, void* d_ws, size_t ws_size,
                              hipStream_t stream) {
  const float* z_src = (const float*)d_in[0];
  const float* z_dst = (const float*)d_in[1];
  const int*   eidx  = (const int*)d_in[2];
  const float* W1    = (const float*)d_in[3];
  const float* b1    = (const float*)d_in[4];
  const float* W2    = (const float*)d_in[5];
  const float* b2    = (const float*)d_in[6];
  float* out = (float*)d_out;

  const int NH   = in_sizes[0];       // 12,800,000
  const int E    = in_sizes[2] / 2;   // 1,000,000
  const int W1n  = in_sizes[3];       // 32,768
  const int nblk = (E + TILE_E - 1) / TILE_E;   // 15625

  const size_t need = ((size_t)NH * 2 + (size_t)W1n) * sizeof(unsigned short);
  if (ws_size >= need) {
    unsigned short* zsb = (unsigned short*)d_ws;
    unsigned short* zdb = zsb + NH;
    unsigned short* w1b = zdb + NH;
    cvt3_kernel<<<8192, 256, 0, stream>>>(z_src, zsb, NH / 4,
                                          z_dst, zdb, NH / 4,
                                          W1, w1b, W1n / 4);
    edge_decoder<true><<<nblk, 256, 0, stream>>>(
        nullptr, nullptr, zsb, zdb, eidx, nullptr, w1b, b1, W2, b2, out, E);
  } else {
    edge_decoder<false><<<nblk, 256, 0, stream>>>(
        z_src, z_dst, nullptr, nullptr, eidx, W1, nullptr, b1, W2, b2, out, E);
  }
}

// Round 3
// 223.369 us; speedup vs baseline: 1.9857x; 1.2772x over previous
//
#include <hip/hip_runtime.h>

#define HID    128     // hidden width per half
#define K256   256
#define TILE_M 64
#define TILE_E 64

typedef __attribute__((ext_vector_type(8))) short bf16x8;
typedef __attribute__((ext_vector_type(4))) float floatx4;

__device__ __forceinline__ unsigned short f2bf(float f) {
  union { float f; unsigned u; } v; v.f = f;
  return (unsigned short)((v.u + 0x7FFFu + ((v.u >> 16) & 1u)) >> 16);  // RNE
}
__device__ __forceinline__ float bf2f(short s) {
  union { unsigned u; float f; } v; v.u = ((unsigned)(unsigned short)s) << 16;
  return v.f;
}
__device__ __forceinline__ bf16x8 pack8(float4 a, float4 b) {
  bf16x8 r;
  r[0] = (short)f2bf(a.x); r[1] = (short)f2bf(a.y);
  r[2] = (short)f2bf(a.z); r[3] = (short)f2bf(a.w);
  r[4] = (short)f2bf(b.x); r[5] = (short)f2bf(b.y);
  r[6] = (short)f2bf(b.z); r[7] = (short)f2bf(b.w);
  return r;
}

// ---------------- Phase 1: H = z * W1halfT  (M x 128, K=128) ----------------
// blockIdx.y selects table: 0 -> Hs = zs * W1[:, 0:128]^T, 1 -> Hd = zd * W1[:,128:256]^T.
// Converts z fp32->bf16 on the fly (no separate cvt pass). 16 KB LDS A-tile, XOR swizzle.
__global__ __launch_bounds__(256, 4)
void node_proj(const float* __restrict__ zs, const float* __restrict__ zd,
               const float* __restrict__ W1,
               unsigned short* __restrict__ Hs, unsigned short* __restrict__ Hd,
               int M)
{
  __shared__ unsigned short At[TILE_M * HID];  // 16 KiB

  const int which = blockIdx.y;
  const float* __restrict__ z = which ? zd : zs;
  unsigned short* __restrict__ H = which ? Hd : Hs;
  const int koff = which * HID;

  const int tid  = threadIdx.x;
  const int lane = tid & 63;
  const int w    = tid >> 6;
  const int nlo  = lane & 15;
  const int quad = lane >> 4;
  const int r0   = blockIdx.x * TILE_M;

  // stage A-tile (fp32 -> bf16), 1024 16B chunks
#pragma unroll
  for (int i = 0; i < 4; ++i) {
    const int c   = tid + i * 256;
    const int row = c >> 4;
    const int c16 = c & 15;
    const int gr  = r0 + row;
    bf16x8 v = (bf16x8){0,0,0,0,0,0,0,0};
    if (gr < M) {
      const float* p = z + (size_t)gr * HID + c16 * 8;
      v = pack8(*(const float4*)p, *(const float4*)(p + 4));
    }
    *(bf16x8*)(At + row * HID + ((c16 ^ (row & 15)) * 8)) = v;
  }

  // B-fragments for this wave's 32 output cols
  bf16x8 bfr[2][4];
  const int nb = w * 32;
#pragma unroll
  for (int nt = 0; nt < 2; ++nt) {
    const int n = nb + nt * 16 + nlo;
#pragma unroll
    for (int kt = 0; kt < 4; ++kt) {
      const float* p = W1 + (size_t)n * K256 + koff + kt * 32 + quad * 8;
      bfr[nt][kt] = pack8(*(const float4*)p, *(const float4*)(p + 4));
    }
  }
  __syncthreads();

  floatx4 acc[4][2];
#pragma unroll
  for (int mt = 0; mt < 4; ++mt)
#pragma unroll
    for (int nt = 0; nt < 2; ++nt)
      acc[mt][nt] = (floatx4){0.f, 0.f, 0.f, 0.f};

#pragma unroll
  for (int kt = 0; kt < 4; ++kt) {
    bf16x8 a[4];
#pragma unroll
    for (int mt = 0; mt < 4; ++mt) {
      const int m  = mt * 16 + nlo;
      const int cs = (kt * 4 + quad) ^ nlo;
      a[mt] = *(const bf16x8*)(At + m * HID + cs * 8);
    }
#pragma unroll
    for (int mt = 0; mt < 4; ++mt)
#pragma unroll
      for (int nt = 0; nt < 2; ++nt)
        acc[mt][nt] = __builtin_amdgcn_mfma_f32_16x16x32_bf16(
            a[mt], bfr[nt][kt], acc[mt][nt], 0, 0, 0);
  }

  // store H (bf16): row = r0 + mt*16 + quad*4 + r, col = nb + nt*16 + nlo
#pragma unroll
  for (int mt = 0; mt < 4; ++mt) {
#pragma unroll
    for (int r = 0; r < 4; ++r) {
      const int row = r0 + mt * 16 + quad * 4 + r;
      if (row < M) {
#pragma unroll
        for (int nt = 0; nt < 2; ++nt)
          H[(size_t)row * HID + nb + nt * 16 + nlo] = f2bf(acc[mt][nt][r]);
      }
    }
  }
}

// ---------------- Phase 2: out[e] = W2 . relu(Hs[row]+Hd[col]+b1) + b2 ----------------
// 16 lanes per edge (each lane covers 8 cols), 4 edges per 16-lane group per iter.
// Zero LDS, low VGPR -> high occupancy; 8 independent 16B gathers per lane per iter.
__global__ __launch_bounds__(256, 6)
void edge_eval(const unsigned short* __restrict__ Hs,
               const unsigned short* __restrict__ Hd,
               const int* __restrict__ eidx,
               const float* __restrict__ b1, const float* __restrict__ W2,
               const float* __restrict__ b2,
               float* __restrict__ out, int E)
{
  const int tid = threadIdx.x;
  const int l16 = tid & 15;

  float b1v[8], w2v[8];
#pragma unroll
  for (int j = 0; j < 8; ++j) {
    b1v[j] = b1[l16 * 8 + j];
    w2v[j] = W2[l16 * 8 + j];
  }
  const float bias2 = b2[0];

  const int nq    = (E + 3) >> 2;
  const int qstep = gridDim.x * 16;
  for (int q = blockIdx.x * 16 + (tid >> 4); q < nq; q += qstep) {
    const int ebase = q * 4;
    int rows[4], cols[4];
#pragma unroll
    for (int u = 0; u < 4; ++u) {
      const int e = ebase + u;
      const bool ok = e < E;
      rows[u] = ok ? eidx[e] : 0;
      cols[u] = ok ? eidx[E + e] : 0;
    }
    bf16x8 hs[4], hd[4];
#pragma unroll
    for (int u = 0; u < 4; ++u)
      hs[u] = *(const bf16x8*)(Hs + (size_t)rows[u] * HID + l16 * 8);
#pragma unroll
    for (int u = 0; u < 4; ++u)
      hd[u] = *(const bf16x8*)(Hd + (size_t)cols[u] * HID + l16 * 8);

    float v[4];
#pragma unroll
    for (int u = 0; u < 4; ++u) {
      float s = 0.f;
#pragma unroll
      for (int j = 0; j < 8; ++j) {
        float x = bf2f(hs[u][j]) + bf2f(hd[u][j]) + b1v[j];
        x = fmaxf(x, 0.f);
        s = fmaf(x, w2v[j], s);
      }
      s += __shfl_xor(s, 1);
      s += __shfl_xor(s, 2);
      s += __shfl_xor(s, 4);
      s += __shfl_xor(s, 8);
      v[u] = s;
    }
    if (l16 < 4) {
      const int e = ebase + l16;
      const float vo = (l16 == 0) ? v[0] : (l16 == 1) ? v[1] : (l16 == 2) ? v[2] : v[3];
      if (e < E) out[e] = vo + bias2;
    }
  }
}

// ---------------- Fallback (ws too small): R2 fused kernel, fp32 direct ----------------
__global__ __launch_bounds__(256, 4)
void edge_decoder_f32(const float* __restrict__ zsrc_f, const float* __restrict__ zdst_f,
                      const int* __restrict__ eidx,
                      const float* __restrict__ W1f,
                      const float* __restrict__ b1, const float* __restrict__ W2,
                      const float* __restrict__ b2,
                      float* __restrict__ out, int E)
{
  __shared__ unsigned short Zt[TILE_E * K256];
  __shared__ int   idxs[2 * TILE_E];
  __shared__ float part[4 * TILE_E];

  const int tid  = threadIdx.x;
  const int lane = tid & 63;
  const int nh   = tid >> 6;
  const int nlo  = lane & 15;
  const int quad = lane >> 4;
  const int e0   = blockIdx.x * TILE_E;

  if (tid < 2 * TILE_E) {
    const int ee = e0 + (tid & 63);
    idxs[tid] = (ee < E) ? eidx[(tid >> 6) * E + ee] : 0;
  }
  __syncthreads();

#pragma unroll
  for (int it = 0; it < 8; ++it) {
    const int c   = tid + it * 256;
    const int row = c >> 4;
    const int l16 = c & 15;
    const int e   = row >> 1;
    const int h   = row & 1;
    const int node = idxs[h * TILE_E + e];
    const int cs  = ((h << 4) | l16) ^ (e & 31);
    const float* p = (h ? zdst_f : zsrc_f) + (size_t)node * HID + l16 * 8;
    bf16x8 v = pack8(*(const float4*)p, *(const float4*)(p + 4));
    *(bf16x8*)(Zt + e * K256 + cs * 8) = v;
  }
  __syncthreads();

  bf16x8 w1f[2][8];
  const int nb = nh * 32;
#pragma unroll
  for (int nt = 0; nt < 2; ++nt) {
    const int n = nb + nt * 16 + nlo;
#pragma unroll
    for (int kt = 0; kt < 8; ++kt) {
      const float* p = W1f + (size_t)n * K256 + kt * 32 + quad * 8;
      w1f[nt][kt] = pack8(*(const float4*)p, *(const float4*)(p + 4));
    }
  }

  floatx4 acc[4][2];
#pragma unroll
  for (int mt = 0; mt < 4; ++mt)
#pragma unroll
    for (int nt = 0; nt < 2; ++nt)
      acc[mt][nt] = (floatx4){0.f, 0.f, 0.f, 0.f};

#pragma unroll
  for (int kt = 0; kt < 8; ++kt) {
    bf16x8 a[4];
#pragma unroll
    for (int mt = 0; mt < 4; ++mt) {
      const int m  = mt * 16 + nlo;
      const int cs = (kt * 4 + quad) ^ (m & 31);
      a[mt] = *(const bf16x8*)(Zt + m * K256 + cs * 8);
    }
#pragma unroll
    for (int mt = 0; mt < 4; ++mt)
#pragma unroll
      for (int nt = 0; nt < 2; ++nt)
        acc[mt][nt] = __builtin_amdgcn_mfma_f32_16x16x32_bf16(
            a[mt], w1f[nt][kt], acc[mt][nt], 0, 0, 0);
  }

  float b1v[2], w2v[2];
#pragma unroll
  for (int nt = 0; nt < 2; ++nt) {
    const int n = nb + nt * 16 + nlo;
    b1v[nt] = b1[n];
    w2v[nt] = W2[n];
  }
#pragma unroll
  for (int mt = 0; mt < 4; ++mt) {
#pragma unroll
    for (int r = 0; r < 4; ++r) {
      float v = 0.f;
#pragma unroll
      for (int nt = 0; nt < 2; ++nt) {
        float x = acc[mt][nt][r] + b1v[nt];
        x = fmaxf(x, 0.f);
        v = fmaf(x, w2v[nt], v);
      }
      v += __shfl_xor(v, 1);
      v += __shfl_xor(v, 2);
      v += __shfl_xor(v, 4);
      v += __shfl_xor(v, 8);
      if (nlo == 0)
        part[nh * TILE_E + mt * 16 + quad * 4 + r] = v;
    }
  }
  __syncthreads();
  if (tid < TILE_E && e0 + tid < E)
    out[e0 + tid] = part[tid] + part[TILE_E + tid] + part[2 * TILE_E + tid]
                  + part[3 * TILE_E + tid] + b2[0];
}

extern "C" void kernel_launch(void* const* d_in, const int* in_sizes, int n_in,
                              void* d_out, int out_size, void* d_ws, size_t ws_size,
                              hipStream_t stream) {
  const float* z_src = (const float*)d_in[0];
  const float* z_dst = (const float*)d_in[1];
  const int*   eidx  = (const int*)d_in[2];
  const float* W1    = (const float*)d_in[3];
  const float* b1    = (const float*)d_in[4];
  const float* W2    = (const float*)d_in[5];
  const float* b2    = (const float*)d_in[6];
  float* out = (float*)d_out;

  const int NH = in_sizes[0];        // 12,800,000 = M * 128
  const int M  = NH / HID;           // 100,000
  const int E  = in_sizes[2] / 2;    // 1,000,000

  const size_t need = (size_t)M * HID * 2 * sizeof(unsigned short);  // Hs + Hd
  if (ws_size >= need) {
    unsigned short* Hs = (unsigned short*)d_ws;
    unsigned short* Hd = Hs + (size_t)M * HID;
    const int nMt = (M + TILE_M - 1) / TILE_M;   // 1563
    node_proj<<<dim3(nMt, 2), 256, 0, stream>>>(z_src, z_dst, W1, Hs, Hd, M);
    edge_eval<<<4096, 256, 0, stream>>>(Hs, Hd, eidx, b1, W2, b2, out, E);
  } else {
    const int nblk = (E + TILE_E - 1) / TILE_E;
    edge_decoder_f32<<<nblk, 256, 0, stream>>>(z_src, z_dst, eidx, W1, b1, W2, b2, out, E);
  }
}